// Round 7
// baseline (281.411 us; speedup 1.0000x reference)
//
#include <hip/hip_runtime.h>
#include <hip/hip_bf16.h>
#include <cstdint>
#include <cstddef>

// Problem constants (L=256, C=20, LC=5120, BATCH=1024)
#define LCN 5120
#define BN  1024
#define CN  20

typedef __attribute__((ext_vector_type(4))) float  floatx4;
typedef __attribute__((ext_vector_type(8))) short  shortx8;
typedef __attribute__((ext_vector_type(4))) unsigned short ushortx4;

static __device__ __forceinline__ unsigned short f2bf(float f) {
    __hip_bfloat16 h = __float2bfloat16(f);
    return *reinterpret_cast<unsigned short*>(&h);
}

// ---------------------------------------------------------------------------
// Pass 1a: streaming masked convert, NATIVE layout (reverted to R4/R5 form).
//   Tn[a*5120 + k] = bf16(theta[a*5120 + k]) if k >= 20*(a/20+1) else 0
// ---------------------------------------------------------------------------
__global__ __launch_bounds__(256) void k_conv(const float* __restrict__ th,
                                              unsigned short* __restrict__ Tn) {
    const int a  = blockIdx.y;
    const int t  = a >> 7;
    const int c0 = (CN * ((128 * t) / CN + 1)) / 512;
    const int bx = blockIdx.x;
    if (2 * (bx + 1) <= c0) return;
    const int kmin = CN * (a / CN + 1);
    const int col  = bx * 1024 + threadIdx.x * 4;
    const floatx4 v = *reinterpret_cast<const floatx4*>(th + (size_t)a * LCN + col);
    ushortx4 o;
#pragma unroll
    for (int e = 0; e < 4; ++e)
        o[e] = (col + e >= kmin) ? f2bf(v[e]) : (unsigned short)0;
    *reinterpret_cast<ushortx4*>(Tn + (size_t)a * LCN + col) = o;
}

// ---------------------------------------------------------------------------
// Pass 1b: fused lin-term + x convert (unchanged).
// ---------------------------------------------------------------------------
__global__ __launch_bounds__(256) void k_init(const float* __restrict__ x,
                                              const float* __restrict__ th0,
                                              const float* __restrict__ thlc,
                                              float* __restrict__ out,
                                              unsigned short* __restrict__ Xb) {
    const int b = blockIdx.x;
    const int tid = threadIdx.x;
    const floatx4* xr = reinterpret_cast<const floatx4*>(x + (size_t)b * LCN);
    const floatx4* tr = reinterpret_cast<const floatx4*>(thlc);
    ushortx4* xw = reinterpret_cast<ushortx4*>(Xb + (size_t)b * LCN);
    float s = 0.0f;
    for (int k = tid; k < LCN / 4; k += 256) {
        const floatx4 a = xr[k], t2 = tr[k];
        s += a[0] * t2[0] + a[1] * t2[1] + a[2] * t2[2] + a[3] * t2[3];
        ushortx4 o;
#pragma unroll
        for (int e = 0; e < 4; ++e) o[e] = f2bf(a[e]);
        xw[k] = o;
    }
#pragma unroll
    for (int off = 32; off > 0; off >>= 1) s += __shfl_down(s, off, 64);
    __shared__ float ws4[4];
    if ((tid & 63) == 0) ws4[tid >> 6] = s;
    __syncthreads();
    if (tid == 0) out[b] = th0[0] + ws4[0] + ws4[1] + ws4[2] + ws4[3];
}

// ---------------------------------------------------------------------------
// Pass 2: masked-GEMM + fused dot-reduce — LDS-FREE K-LOOP (R7).
// MFMA fragments are 16B-contiguous per lane in BOTH operands (A rows from
// Xb, B rows from Tn, both k-major), so fragments load global->VGPR directly.
// NO LDS staging, NO __syncthreads in the K-loop: each wave is an independent
// stream of global_load_dwordx4 (immediate offsets, bases precomputed) +
// MFMA, letting the compiler pipeline with vmcnt(N) and waves interleave
// freely. This removes the vmcnt(0)-drain barrier that capped R2-R6 at 72us.
// Cost: 2x L2 traffic (waves duplicate A/B halves) - L2 has ~5x headroom.
// XCD-pinned decode kept. Epilogue unchanged.
// ---------------------------------------------------------------------------
__global__ __launch_bounds__(256) void k_quad(
    const unsigned short* __restrict__ Xb,   // [1024][5120] bf16
    const unsigned short* __restrict__ Tn,   // [5120][5120] bf16, native rows
    float*                __restrict__ out,  // [1024]
    const int tot)                           // total chunk count (220)
{
    const int bid  = blockIdx.x;
    const int xcd  = bid & 7;
    const int slot = bid >> 3;
    const int m    = slot & 7;
    const int g    = slot >> 3;
    int q = g * 8 + xcd;
    if (q >= tot) return;

    __shared__ float partial[128];

    const int tid  = threadIdx.x;
    const int lane = tid & 63;
    const int w    = tid >> 6;        // wave 0..3
    const int wm   = w & 1;
    const int wn   = w >> 1;
    const int lrow = lane & 15;
    const int kq   = lane >> 4;

    // map chunk ordinal q -> (n-tile, absolute chunk c)
    int n = 0, c = 0;
    for (int t = 0; t < 40; ++t) {
        const int c0t = (CN * ((128 * t) / CN + 1)) / 512;
        const int chn = 10 - c0t;
        if (q < chn) { n = t; c = c0t + q; break; }
        q -= chn;
    }
    const int b0 = m * 128;
    const int n0 = n * 128;
    const int k0 = c * 512;

    if (tid < 128) partial[tid] = 0.0f;

    floatx4 acc[4][4];
#pragma unroll
    for (int mt = 0; mt < 4; ++mt)
#pragma unroll
        for (int nt = 0; nt < 4; ++nt) acc[mt][nt] = (floatx4)0.0f;

    // per-lane fragment base pointers (16B-aligned: k0%512==0, kq*8 elems)
    const unsigned short* ap[4];
    const unsigned short* bp[4];
#pragma unroll
    for (int mt = 0; mt < 4; ++mt)
        ap[mt] = Xb + (size_t)(b0 + wm * 64 + mt * 16 + lrow) * LCN + k0 + kq * 8;
#pragma unroll
    for (int nt = 0; nt < 4; ++nt)
        bp[nt] = Tn + (size_t)(n0 + wn * 64 + nt * 16 + lrow) * LCN + k0 + kq * 8;

    // barrier-free K-loop: 16 x (8 loads + 16 MFMA); offsets kk*32 elems
    // (kk*64 bytes) are immediates after unroll.
#pragma unroll
    for (int kk = 0; kk < 16; ++kk) {
        shortx8 af[4], bfr[4];
#pragma unroll
        for (int mt = 0; mt < 4; ++mt)
            af[mt] = *reinterpret_cast<const shortx8*>(ap[mt] + kk * 32);
#pragma unroll
        for (int nt = 0; nt < 4; ++nt)
            bfr[nt] = *reinterpret_cast<const shortx8*>(bp[nt] + kk * 32);
#pragma unroll
        for (int mt = 0; mt < 4; ++mt)
#pragma unroll
            for (int nt = 0; nt < 4; ++nt)
                acc[mt][nt] = __builtin_amdgcn_mfma_f32_16x16x32_bf16(af[mt], bfr[nt], acc[mt][nt], 0, 0, 0);
    }

    __syncthreads();   // partial[] zero-init visible before epilogue atomics

    // Epilogue: C/D layout col = lane&15 (a), row = quad*4 + reg (b)
#pragma unroll
    for (int mt = 0; mt < 4; ++mt) {
#pragma unroll
        for (int r = 0; r < 4; ++r) {
            const int b = b0 + wm * 64 + mt * 16 + kq * 4 + r;
            float s = 0.0f;
#pragma unroll
            for (int nt = 0; nt < 4; ++nt) {
                const int a = n0 + wn * 64 + nt * 16 + lrow;
                const __hip_bfloat16 hv = *reinterpret_cast<const __hip_bfloat16*>(&Xb[(size_t)b * LCN + a]);
                s += acc[mt][nt][r] * __bfloat162float(hv);
            }
            s += __shfl_xor(s, 1, 64);
            s += __shfl_xor(s, 2, 64);
            s += __shfl_xor(s, 4, 64);
            s += __shfl_xor(s, 8, 64);
            if (lrow == 0) atomicAdd(&partial[b - b0], s);
        }
    }
    __syncthreads();
    if (tid < 128) atomicAdd(&out[b0 + tid], partial[tid]);
}

// ---------------------------------------------------------------------------
extern "C" void kernel_launch(void* const* d_in, const int* in_sizes, int n_in,
                              void* d_out, int out_size, void* d_ws, size_t ws_size,
                              hipStream_t stream) {
    const float* x      = (const float*)d_in[0];
    const float* th0    = (const float*)d_in[1];
    const float* thlc   = (const float*)d_in[2];
    const float* thlclc = (const float*)d_in[3];
    float* out = (float*)d_out;

    // ws layout: Tn (bf16 5120x5120 = 52.4 MB) | Xb (bf16 1024x5120 = 10.5 MB)
    unsigned short* Tn = (unsigned short*)d_ws;
    unsigned short* Xb = (unsigned short*)((char*)d_ws + (size_t)LCN * LCN * 2);

    k_conv<<<dim3(LCN / 1024, LCN), 256, 0, stream>>>(thlclc, Tn);
    k_init<<<dim3(BN), 256, 0, stream>>>(x, th0, thlc, out, Xb);

    int tot = 0;
    for (int t = 0; t < 40; ++t) {
        const int c0t = (CN * ((128 * t) / CN + 1)) / 512;
        tot += 10 - c0t;
    }
    const int groups = (tot + 7) / 8;             // 28
    k_quad<<<dim3(groups * 64), 256, 0, stream>>>(Xb, Tn, out, tot);
}

// Round 8
// 243.395 us; speedup vs baseline: 1.1562x; 1.1562x over previous
//
#include <hip/hip_runtime.h>
#include <hip/hip_bf16.h>
#include <cstdint>
#include <cstddef>

// Problem constants (L=256, C=20, LC=5120, BATCH=1024)
#define LCN 5120
#define BN  1024
#define CN  20

typedef __attribute__((ext_vector_type(4))) float  floatx4;
typedef __attribute__((ext_vector_type(8))) short  shortx8;
typedef __attribute__((ext_vector_type(4))) unsigned short ushortx4;

static __device__ __forceinline__ unsigned short f2bf(float f) {
    __hip_bfloat16 h = __float2bfloat16(f);
    return *reinterpret_cast<unsigned short*>(&h);
}

static __device__ __forceinline__ void gload_lds16(const void* g, void* l) {
    __builtin_amdgcn_global_load_lds(
        (const __attribute__((address_space(1))) void*)g,
        (__attribute__((address_space(3))) void*)l,
        16, 0, 0);
}

// ---------------------------------------------------------------------------
// Pass 1a: streaming masked convert, NATIVE layout (unchanged).
//   Tn[a*5120 + k] = bf16(theta[a*5120 + k]) if k >= 20*(a/20+1) else 0
// ---------------------------------------------------------------------------
__global__ __launch_bounds__(256) void k_conv(const float* __restrict__ th,
                                              unsigned short* __restrict__ Tn) {
    const int a  = blockIdx.y;
    const int t  = a >> 7;
    const int c0 = (CN * ((128 * t) / CN + 1)) / 512;
    const int bx = blockIdx.x;
    if (2 * (bx + 1) <= c0) return;
    const int kmin = CN * (a / CN + 1);
    const int col  = bx * 1024 + threadIdx.x * 4;
    const floatx4 v = *reinterpret_cast<const floatx4*>(th + (size_t)a * LCN + col);
    ushortx4 o;
#pragma unroll
    for (int e = 0; e < 4; ++e)
        o[e] = (col + e >= kmin) ? f2bf(v[e]) : (unsigned short)0;
    *reinterpret_cast<ushortx4*>(Tn + (size_t)a * LCN + col) = o;
}

// ---------------------------------------------------------------------------
// Pass 1b: fused lin-term + x convert (unchanged).
// ---------------------------------------------------------------------------
__global__ __launch_bounds__(256) void k_init(const float* __restrict__ x,
                                              const float* __restrict__ th0,
                                              const float* __restrict__ thlc,
                                              float* __restrict__ out,
                                              unsigned short* __restrict__ Xb) {
    const int b = blockIdx.x;
    const int tid = threadIdx.x;
    const floatx4* xr = reinterpret_cast<const floatx4*>(x + (size_t)b * LCN);
    const floatx4* tr = reinterpret_cast<const floatx4*>(thlc);
    ushortx4* xw = reinterpret_cast<ushortx4*>(Xb + (size_t)b * LCN);
    float s = 0.0f;
    for (int k = tid; k < LCN / 4; k += 256) {
        const floatx4 a = xr[k], t2 = tr[k];
        s += a[0] * t2[0] + a[1] * t2[1] + a[2] * t2[2] + a[3] * t2[3];
        ushortx4 o;
#pragma unroll
        for (int e = 0; e < 4; ++e) o[e] = f2bf(a[e]);
        xw[k] = o;
    }
#pragma unroll
    for (int off = 32; off > 0; off >>= 1) s += __shfl_down(s, off, 64);
    __shared__ float ws4[4];
    if ((tid & 63) == 0) ws4[tid >> 6] = s;
    __syncthreads();
    if (tid == 0) out[b] = th0[0] + ws4[0] + ws4[1] + ws4[2] + ws4[3];
}

// ---------------------------------------------------------------------------
// Pass 2 (R8): masked-GEMM + fused dot-reduce with SMALL TILES FOR TLP.
// 64x64 tile, 4 waves, each wave 2x2 of 16x16x32 MFMA (16 AGPR acc, ~70 regs
// -> 5-6 waves/SIMD resident vs ~2-3 before). Grid 220 chunks x 16 m x 2 nh
// = 7040 blocks (27.5/CU). Rationale: all throughput pipes were <20% while
// per-iter slots measured ~1570 cyc -> latency-bound with only ~8 waves/CU;
// quadruple the resident waves to hide ~900-cyc cold-L3 HBM latency.
// XCD-pinned decode + zero-conflict segment swizzle + suffix chunk table kept.
//   bid = slot*8 + xcd, slot = g*32 + s, s: m = s&15 (64-row band),
//   nh = s>>4 (64-col half of the 128-wide n-tile), chunk q = g*8 + xcd.
// ---------------------------------------------------------------------------
__global__ __launch_bounds__(256, 5) void k_quad(
    const unsigned short* __restrict__ Xb,   // [1024][5120] bf16
    const unsigned short* __restrict__ Tn,   // [5120][5120] bf16, native rows
    float*                __restrict__ out,  // [1024]
    const int tot)                           // total chunk count (220)
{
    const int bid  = blockIdx.x;
    const int xcd  = bid & 7;
    const int slot = bid >> 3;
    const int s    = slot & 31;
    const int g    = slot >> 5;
    const int m    = s & 15;
    const int nh   = s >> 4;
    int q = g * 8 + xcd;
    if (q >= tot) return;

    __shared__ unsigned short As[64 * 32];   // 4 KB
    __shared__ unsigned short Bs[64 * 32];   // 4 KB
    __shared__ float partial[64];

    const int tid  = threadIdx.x;
    const int lane = tid & 63;
    const int w    = tid >> 6;        // wave 0..3
    const int wm   = w & 1;           // 32-row half of A band
    const int wn   = w >> 1;          // 32-row half of B band
    const int lrow = lane & 15;
    const int kq   = lane >> 4;       // 0..3

    // map chunk ordinal q -> (n-tile, absolute chunk c)
    int n = 0, c = 0;
    for (int t = 0; t < 40; ++t) {
        const int c0t = (CN * ((128 * t) / CN + 1)) / 512;
        const int chn = 10 - c0t;
        if (q < chn) { n = t; c = c0t + q; break; }
        q -= chn;
    }
    const int b0 = m * 64;
    const int n0 = n * 128 + nh * 64;
    const int k0 = c * 512;

    if (tid < 64) partial[tid] = 0.0f;

    floatx4 acc[2][2];
#pragma unroll
    for (int mt = 0; mt < 2; ++mt)
#pragma unroll
        for (int nt = 0; nt < 2; ++nt) acc[mt][nt] = (floatx4)0.0f;

    // staging: 256 slots of 16B per tile, 1 per thread per tile.
    // LDS slot (row, lseg) holds global seg gseg = (lseg - (row>>1)) & 3.
    const int srow  = tid >> 2;
    const int gseg  = ((tid & 3) - (srow >> 1)) & 3;
    const unsigned short* agp = Xb + (size_t)(b0 + srow) * LCN + k0 + gseg * 8;
    const unsigned short* bgp = Tn + (size_t)(n0 + srow) * LCN + k0 + gseg * 8;
    char* const la = (char*)As + (size_t)(w * 64) * 16;   // wave-uniform dest
    char* const lb = (char*)Bs + (size_t)(w * 64) * 16;

    // swizzled fragment offsets (ushort units): seg = (kq + (row>>1)) & 3
    int aoff[2], boff[2];
#pragma unroll
    for (int mt = 0; mt < 2; ++mt) {
        const int row = wm * 32 + mt * 16 + lrow;
        aoff[mt] = row * 32 + (((kq + (row >> 1)) & 3) << 3);
    }
#pragma unroll
    for (int nt = 0; nt < 2; ++nt) {
        const int row = wn * 32 + nt * 16 + lrow;
        boff[nt] = row * 32 + (((kq + (row >> 1)) & 3) << 3);
    }

    for (int kk = 0; kk < 16; ++kk) {
        const int kc = kk * 64;      // element offset kk*32 -> bytes kk*64
        gload_lds16((const char*)agp + (size_t)kc, la);
        gload_lds16((const char*)bgp + (size_t)kc, lb);
        __syncthreads();

        shortx8 af[2], bfr[2];
#pragma unroll
        for (int mt = 0; mt < 2; ++mt)
            af[mt] = *reinterpret_cast<const shortx8*>(As + aoff[mt]);
#pragma unroll
        for (int nt = 0; nt < 2; ++nt)
            bfr[nt] = *reinterpret_cast<const shortx8*>(Bs + boff[nt]);
#pragma unroll
        for (int mt = 0; mt < 2; ++mt)
#pragma unroll
            for (int nt = 0; nt < 2; ++nt)
                acc[mt][nt] = __builtin_amdgcn_mfma_f32_16x16x32_bf16(af[mt], bfr[nt], acc[mt][nt], 0, 0, 0);
        __syncthreads();
    }

    // Epilogue: C/D layout col = lane&15 (a), row = kq*4 + r (b)
#pragma unroll
    for (int mt = 0; mt < 2; ++mt) {
#pragma unroll
        for (int r = 0; r < 4; ++r) {
            const int b = b0 + wm * 32 + mt * 16 + kq * 4 + r;
            float sv = 0.0f;
#pragma unroll
            for (int nt = 0; nt < 2; ++nt) {
                const int a = n0 + wn * 32 + nt * 16 + lrow;
                const __hip_bfloat16 hv = *reinterpret_cast<const __hip_bfloat16*>(&Xb[(size_t)b * LCN + a]);
                sv += acc[mt][nt][r] * __bfloat162float(hv);
            }
            sv += __shfl_xor(sv, 1, 64);
            sv += __shfl_xor(sv, 2, 64);
            sv += __shfl_xor(sv, 4, 64);
            sv += __shfl_xor(sv, 8, 64);
            if (lrow == 0) atomicAdd(&partial[b - b0], sv);
        }
    }
    __syncthreads();
    if (tid < 64) atomicAdd(&out[b0 + tid], partial[tid]);
}

// ---------------------------------------------------------------------------
extern "C" void kernel_launch(void* const* d_in, const int* in_sizes, int n_in,
                              void* d_out, int out_size, void* d_ws, size_t ws_size,
                              hipStream_t stream) {
    const float* x      = (const float*)d_in[0];
    const float* th0    = (const float*)d_in[1];
    const float* thlc   = (const float*)d_in[2];
    const float* thlclc = (const float*)d_in[3];
    float* out = (float*)d_out;

    // ws layout: Tn (bf16 5120x5120 = 52.4 MB) | Xb (bf16 1024x5120 = 10.5 MB)
    unsigned short* Tn = (unsigned short*)d_ws;
    unsigned short* Xb = (unsigned short*)((char*)d_ws + (size_t)LCN * LCN * 2);

    k_conv<<<dim3(LCN / 1024, LCN), 256, 0, stream>>>(thlclc, Tn);
    k_init<<<dim3(BN), 256, 0, stream>>>(x, th0, thlc, out, Xb);

    int tot = 0;
    for (int t = 0; t < 40; ++t) {
        const int c0t = (CN * ((128 * t) / CN + 1)) / 512;
        tot += 10 - c0t;
    }
    const int groups = (tot + 7) / 8;             // 28
    // bid = ((g*32 + s)*8 + xcd): 28 groups x 32 sub-tiles x 8 xcd
    k_quad<<<dim3(groups * 32 * 8), 256, 0, stream>>>(Xb, Tn, out, tot);
}